// Round 11
// baseline (113.470 us; speedup 1.0000x reference)
//
#include <hip/hip_runtime.h>
#include <hip/hip_bf16.h>
#include <math.h>
#include <string.h>

#define BB   16
#define NN   128
#define NCC  32
#define HH   256
#define AA   64
#define DEGN 3
#define BNR  (BB*NN)   // 2048 rows

typedef __bf16 bf16x8 __attribute__((ext_vector_type(8)));
typedef float  f32x16 __attribute__((ext_vector_type(16)));

__device__ __forceinline__ unsigned int pk2(float lo, float hi) {
    __hip_bfloat162 h2 = __float22bfloat162_rn(make_float2(lo, hi));
    unsigned int u;
    memcpy(&u, &h2, 4);
    return u;
}
__device__ __forceinline__ unsigned short bfbits(float f) {
    __hip_bfloat16 h = __float2bfloat16(f);
    unsigned short u;
    memcpy(&u, &h, 2);
    return u;
}

// ---------------------------------------------------------------------------
// Kernel 1 (k_head): fused prep (unchanged from round 9).
// ---------------------------------------------------------------------------
__global__ __launch_bounds__(256) void k_head(const float* __restrict__ cond,
                                              const float* __restrict__ cmask,
                                              const float* __restrict__ Wc,
                                              const float* __restrict__ W1,
                                              const float* __restrict__ Wlin,
                                              float* __restrict__ dv,
                                              float* __restrict__ dv_out,
                                              unsigned short* __restrict__ W1t,
                                              unsigned short* __restrict__ Wlt) {
    __shared__ float shm[32 * 33];
    const int bid = blockIdx.x, t = threadIdx.x;

    if (bid < 48) {
        const int d = bid >> 4, b = bid & 15;
        float s = 0.f, ms = 0.f;
        for (int c = 0; c < NCC; ++c) {
            float mk = cmask[b * NCC + c];
            s  += cond[(b * NCC + c) * HH + t] * mk;
            ms += mk;
        }
        shm[t] = s / fmaxf(ms, 1.0f);
        __syncthreads();
        const float* Wd = Wc + (size_t)d * HH * HH;
        float acc = 0.f;
        for (int k = 0; k < HH; ++k) acc += shm[k] * Wd[k * HH + t];
        int idx = (d * BB + b) * HH + t;
        dv[idx]     = acc;
        dv_out[idx] = acc;
    } else if (bid < 240) {
        const int q = bid - 48;
        const int d = q >> 6, r2 = q & 63, tk = r2 >> 3, tn = r2 & 7;
        float (*tile)[33] = (float (*)[33])shm;
        #pragma unroll
        for (int p = 0; p < 4; ++p) {
            int kr = p * 8 + (t >> 5), nr = t & 31;
            tile[kr][nr] = W1[((size_t)d * HH + tk * 32 + kr) * HH + tn * 32 + nr];
        }
        __syncthreads();
        #pragma unroll
        for (int p = 0; p < 4; ++p) {
            int nr = p * 8 + (t >> 5), kr = t & 31;
            W1t[((size_t)d * HH + tn * 32 + nr) * HH + tk * 32 + kr] =
                bfbits(tile[kr][nr]);
        }
    } else {
        const int q = bid - 240;
        const int d = q >> 4, r3 = q & 15, tk = r3 >> 1, ta = r3 & 1;
        float (*tile)[33] = (float (*)[33])shm;
        #pragma unroll
        for (int p = 0; p < 4; ++p) {
            int kr = p * 8 + (t >> 5), ar = t & 31;
            tile[kr][ar] = Wlin[((size_t)d * HH + tk * 32 + kr) * AA + ta * 32 + ar];
        }
        __syncthreads();
        #pragma unroll
        for (int p = 0; p < 4; ++p) {
            int ar = p * 8 + (t >> 5), kr = t & 31;
            Wlt[((size_t)d * AA + ta * 32 + ar) * HH + tk * 32 + kr] =
                bfbits(tile[kr][ar]);
        }
    }
}

// ---------------------------------------------------------------------------
// Kernel 2 (k_mlp): fused encoder+linear via bf16 MFMA (unchanged from r9).
// ---------------------------------------------------------------------------
__global__ __launch_bounds__(256) void k_mlp(const float* __restrict__ x,
                                             const float* __restrict__ xmask,
                                             const float* __restrict__ b1,
                                             const float* __restrict__ blin,
                                             const float* __restrict__ dv,
                                             const unsigned short* __restrict__ W1t,
                                             const unsigned short* __restrict__ Wlt,
                                             float* __restrict__ yv) {
    __shared__ __align__(16) char ldsA[32 * 512];
    __shared__ float ps[2][32][68];

    const int t = threadIdx.x;
    const int d = blockIdx.x >> 6, rt = blockIdx.x & 63;
    const int row0 = rt * 32;
    const int b = row0 >> 7;
    const int lane = t & 63, wid = t >> 6;
    const int rl5 = lane & 31, h2v = lane >> 5;

    #pragma unroll
    for (int it = 0; it < 8; ++it) {
        const int r = wid * 8 + it;
        const float4 v = *(const float4*)&x[(size_t)(row0 + r) * HH + lane * 4];
        uint2 u = make_uint2(pk2(v.x, v.y), pk2(v.z, v.w));
        *(uint2*)(ldsA + r * 512 + ((lane * 8) ^ ((r & 7) << 4))) = u;
    }
    __syncthreads();

    f32x16 acc1[2];
    #pragma unroll
    for (int nt = 0; nt < 2; ++nt)
        #pragma unroll
        for (int e = 0; e < 16; ++e) acc1[nt][e] = 0.f;

    #pragma unroll
    for (int ks = 0; ks < 16; ++ks) {
        bf16x8 af = *(const bf16x8*)(ldsA + rl5 * 512 +
                      ((ks * 32 + h2v * 16) ^ ((rl5 & 7) << 4)));
        #pragma unroll
        for (int nt = 0; nt < 2; ++nt) {
            const int n = wid * 64 + nt * 32 + rl5;
            bf16x8 bf = *(const bf16x8*)(W1t +
                          ((size_t)d * HH + n) * HH + ks * 16 + h2v * 8);
            acc1[nt] = __builtin_amdgcn_mfma_f32_32x32x16_bf16(af, bf, acc1[nt], 0, 0, 0);
        }
    }
    __syncthreads();

    #pragma unroll
    for (int nt = 0; nt < 2; ++nt) {
        const int col = wid * 64 + nt * 32 + rl5;
        const float add = b1[d * HH + col] + dv[(d * BB + b) * HH + col];
        #pragma unroll
        for (int e = 0; e < 16; ++e) {
            const int row = (e & 3) + 8 * (e >> 2) + 4 * h2v;
            float v = acc1[nt][e] + add;
            float u = 0.7978845608028654f * (v + 0.044715f * v * v * v);
            float g = 0.5f * v * (1.0f + tanhf(u));
            *(unsigned short*)(ldsA + row * 512 + ((col * 2) ^ ((row & 7) << 4))) =
                bfbits(g);
        }
    }
    __syncthreads();

    const int qc = wid >> 1, kh = wid & 1;
    f32x16 acc2;
    #pragma unroll
    for (int e = 0; e < 16; ++e) acc2[e] = 0.f;
    #pragma unroll
    for (int ks = 0; ks < 8; ++ks) {
        const int kk = kh * 8 + ks;
        bf16x8 af = *(const bf16x8*)(ldsA + rl5 * 512 +
                      ((kk * 32 + h2v * 16) ^ ((rl5 & 7) << 4)));
        bf16x8 bf = *(const bf16x8*)(Wlt +
                      ((size_t)d * AA + qc * 32 + rl5) * HH + kk * 16 + h2v * 8);
        acc2 = __builtin_amdgcn_mfma_f32_32x32x16_bf16(af, bf, acc2, 0, 0, 0);
    }
    #pragma unroll
    for (int e = 0; e < 16; ++e) {
        const int row = (e & 3) + 8 * (e >> 2) + 4 * h2v;
        ps[kh][row][qc * 32 + rl5] = acc2[e];
    }
    __syncthreads();

    #pragma unroll
    for (int j = 0; j < 8; ++j) {
        const int idx = t * 8 + j;
        const int row = idx >> 6, a = idx & 63;
        float v = ps[0][row][a] + ps[1][row][a] + blin[d * AA + a];
        v *= xmask[row0 + row];
        yv[((size_t)d * BNR + row0 + row) * AA + a] = v;
    }
}

// ---------------------------------------------------------------------------
// Kernel 3 (k_contract): B entirely in registers; A through 32KB LDS.
// Same algebra & accumulation order as r8-r10 (bit-identical):
// out*4096 = A1 B1^T + B1 A1^T + A2 B2^T + B2 A2^T per (b,x), with
//   A1[r][k]=s0[k]Y1[r,k]+s1[k]Y0[r,k]; A2=s2.Y0; B1=Y2; B2=Y1.
// B1/B2 are x-invariant: all 40 B fragments (bf[4][4]+af[4] each) are
// loaded ONCE per block from global (L2-resident) with in-register f32->bf16
// convert -> 160 VGPR, zero LDS, zero per-xi reads. Per xi only A is staged
// (32KB LDS); MFMA ds_reads drop 80->40/wave/xi. Epilogue = r10's wave-local
// full-row scheme (scratch in own A rows). 2 barriers/xi; vmcnt never waited.
// ---------------------------------------------------------------------------
__device__ __forceinline__ void lds_fence_barrier() {
    asm volatile("s_waitcnt lgkmcnt(0)" ::: "memory");
    __builtin_amdgcn_s_barrier();
    __builtin_amdgcn_sched_barrier(0);
}
__device__ __forceinline__ void lds_wave_wait() {
    asm volatile("s_waitcnt lgkmcnt(0)" ::: "memory");
    __builtin_amdgcn_sched_barrier(0);
}
// load 8 consecutive f32 from global, convert to bf16x8 (same per-element
// rounding as the old staged path -> bit-identical values)
__device__ __forceinline__ bf16x8 ldfrag(const float* __restrict__ p) {
    float4 v0 = *(const float4*)(p);
    float4 v1 = *(const float4*)(p + 4);
    union { unsigned int u[4]; bf16x8 v; } r;
    r.u[0] = pk2(v0.x, v0.y);
    r.u[1] = pk2(v0.z, v0.w);
    r.u[2] = pk2(v1.x, v1.y);
    r.u[3] = pk2(v1.z, v1.w);
    return r.v;
}

#define LROW 128   // bytes per LDS row (64 bf16)

__global__ __launch_bounds__(256, 2) void k_contract(const float* __restrict__ yv,
                                                     float* __restrict__ outp) {
    __shared__ __align__(16) char lds[2 * 128 * LROW];   // A1 | A2, 16KB each
    char* A1b = lds;
    char* A2b = lds + 128 * LROW;

    const int t  = threadIdx.x;
    const int b  = blockIdx.x >> 5;
    const int xg = blockIdx.x & 31;

    const float* y0p = yv + (size_t)(0 * BNR + b * NN) * AA;
    const float* y1p = yv + (size_t)(1 * BNR + b * NN) * AA;
    const float* y2p = yv + (size_t)(2 * BNR + b * NN) * AA;

    const int lane = t & 63;
    const int wid  = t >> 6;
    const int li   = lane & 31;
    const int rh   = lane >> 5;
    const int rl5  = lane & 31, h2v = lane >> 5;
    const int wy   = wid * 32;           // this wave's output row stripe

    // ---- load ALL B fragments into registers (once per block) ----
    // element offset within a row: k0 = ks*16 + h2v*8 (8 consecutive f32)
    bf16x8 bfB1[4][4], bfB2[4][4];       // [ni][ks]: row = ni*32+rl5
    bf16x8 afB1[4],    afB2[4];          // [ks]:     row = wy+rl5
    #pragma unroll
    for (int ni = 0; ni < 4; ++ni) {
        const int row = ni * 32 + rl5;
        #pragma unroll
        for (int ks = 0; ks < 4; ++ks) {
            const int k0 = ks * 16 + h2v * 8;
            bfB1[ni][ks] = ldfrag(&y2p[row * AA + k0]);
            bfB2[ni][ks] = ldfrag(&y1p[row * AA + k0]);
        }
    }
    #pragma unroll
    for (int ks = 0; ks < 4; ++ks) {
        const int k0 = ks * 16 + h2v * 8;
        afB1[ks] = ldfrag(&y2p[(wy + rl5) * AA + k0]);
        afB2[ks] = ldfrag(&y1p[(wy + rl5) * AA + k0]);
    }

    const float inv = 1.0f / 4096.0f;
    // wave-private epilogue scratch = own A1/A2 row slices (4KB each)
    char* s1 = A1b + wid * 4096;
    char* s2 = A2b + wid * 4096;

    for (int xi = 0; xi < 4; ++xi) {
        const int xr = xg * 4 + xi;
        const float s0 = y0p[xr * AA + lane];
        const float s1v = y1p[xr * AA + lane];
        const float s2v = y2p[xr * AA + lane];
        const float s0a = __shfl(s0, 2 * li),  s0b = __shfl(s0, 2 * li + 1);
        const float s1a = __shfl(s1v, 2 * li), s1b = __shfl(s1v, 2 * li + 1);
        const float s2a = __shfl(s2v, 2 * li), s2b = __shfl(s2v, 2 * li + 1);

        // ---- stage own A1/A2 rows (rows wid*32..+31) ----
        #pragma unroll
        for (int it = 0; it < 16; ++it) {
            const int r   = wid * 32 + it * 2 + rh;
            const int swz = (r & 7) << 4;
            const float2 v0 = *(const float2*)&y0p[r * AA + 2 * li];
            const float2 v1 = *(const float2*)&y1p[r * AA + 2 * li];
            unsigned int a1 = pk2(s0a * v1.x + s1a * v0.x, s0b * v1.y + s1b * v0.y);
            unsigned int a2 = pk2(s2a * v0.x, s2b * v0.y);
            *(unsigned int*)(A1b + r * LROW + ((4 * li) ^ swz)) = a1;
            *(unsigned int*)(A2b + r * LROW + ((4 * li) ^ swz)) = a2;
        }
        lds_fence_barrier();   // bar1: all A staged

        // ---- MFMA, order identical to r10: p0,p1,p2,p3 x ks x ni ----
        f32x16 acc[4];
        #pragma unroll
        for (int ni = 0; ni < 4; ++ni)
            #pragma unroll
            for (int e = 0; e < 16; ++e) acc[ni][e] = 0.f;

        // p0: A1 (own rows, LDS) x B1^T (regs)
        #pragma unroll
        for (int ks = 0; ks < 4; ++ks) {
            const int arow = wy + rl5;
            bf16x8 af = *(const bf16x8*)(A1b + arow * LROW +
                          ((ks * 32 + h2v * 16) ^ ((arow & 7) << 4)));
            #pragma unroll
            for (int ni = 0; ni < 4; ++ni)
                acc[ni] = __builtin_amdgcn_mfma_f32_32x32x16_bf16(
                    af, bfB1[ni][ks], acc[ni], 0, 0, 0);
        }
        // p1: B1 (regs) x A1^T (all rows, LDS)
        #pragma unroll
        for (int ks = 0; ks < 4; ++ks) {
            #pragma unroll
            for (int ni = 0; ni < 4; ++ni) {
                const int brow = ni * 32 + rl5;
                bf16x8 bf = *(const bf16x8*)(A1b + brow * LROW +
                              ((ks * 32 + h2v * 16) ^ ((brow & 7) << 4)));
                acc[ni] = __builtin_amdgcn_mfma_f32_32x32x16_bf16(
                    afB1[ks], bf, acc[ni], 0, 0, 0);
            }
        }
        // p2: A2 x B2^T
        #pragma unroll
        for (int ks = 0; ks < 4; ++ks) {
            const int arow = wy + rl5;
            bf16x8 af = *(const bf16x8*)(A2b + arow * LROW +
                          ((ks * 32 + h2v * 16) ^ ((arow & 7) << 4)));
            #pragma unroll
            for (int ni = 0; ni < 4; ++ni)
                acc[ni] = __builtin_amdgcn_mfma_f32_32x32x16_bf16(
                    af, bfB2[ni][ks], acc[ni], 0, 0, 0);
        }
        // p3: B2 x A2^T
        #pragma unroll
        for (int ks = 0; ks < 4; ++ks) {
            #pragma unroll
            for (int ni = 0; ni < 4; ++ni) {
                const int brow = ni * 32 + rl5;
                bf16x8 bf = *(const bf16x8*)(A2b + brow * LROW +
                              ((ks * 32 + h2v * 16) ^ ((brow & 7) << 4)));
                acc[ni] = __builtin_amdgcn_mfma_f32_32x32x16_bf16(
                    afB2[ks], bf, acc[ni], 0, 0, 0);
            }
        }
        lds_fence_barrier();   // bar2: all A reads done -> region reusable

        // ---- wave-local epilogue (r10 scheme, unchanged) ----
        float* osl = outp + ((size_t)(b * NN + xr)) * (NN * NN);
        #pragma unroll
        for (int half = 0; half < 2; ++half) {
            #pragma unroll
            for (int ni = 0; ni < 4; ++ni) {
                const int colb = ni * 32 + rl5;
                #pragma unroll
                for (int e2 = 0; e2 < 8; ++e2) {
                    const int e    = half * 8 + e2;
                    const int rloc = (e2 & 3) + 8 * (e2 >> 2) + 4 * h2v;
                    char* reg = (e2 < 4) ? s1 : s2;
                    *(float*)(reg + ((rloc & 7) * 512) + colb * 4) =
                        acc[ni][e] * inv;
                }
            }
            lds_wave_wait();
            #pragma unroll
            for (int it2 = 0; it2 < 8; ++it2) {
                const int rloc = it2 * 2 + rh;
                const char* reg = (it2 < 4) ? s1 : s2;
                float4 v = *(const float4*)(reg + ((rloc & 7) * 512) + rl5 * 16);
                *(float4*)&osl[(size_t)(wy + half * 16 + rloc) * NN + rl5 * 4] = v;
            }
            lds_wave_wait();
        }
    }
}

// ---------------------------------------------------------------------------
extern "C" void kernel_launch(void* const* d_in, const int* in_sizes, int n_in,
                              void* d_out, int out_size, void* d_ws, size_t ws_size,
                              hipStream_t stream) {
    const float* x     = (const float*)d_in[0];
    const float* xmask = (const float*)d_in[1];
    const float* cond  = (const float*)d_in[2];
    const float* cmask = (const float*)d_in[3];
    const float* W1    = (const float*)d_in[4];
    const float* b1    = (const float*)d_in[5];
    const float* Wc    = (const float*)d_in[6];
    const float* Wlin  = (const float*)d_in[7];
    const float* blin  = (const float*)d_in[8];

    float* out = (float*)d_out;
    float* ws  = (float*)d_ws;

    float* dv  = ws;                               // 3*16*256 f
    float* yv  = ws + 12288;                       // 3*2048*64 f
    unsigned short* W1t = (unsigned short*)((char*)d_ws + (size_t)(12288 + 393216) * 4);
    unsigned short* Wlt = W1t + (size_t)DEGN * HH * HH;
    float* dv_out = out + (size_t)BB * NN * NN * NN;

    k_head    <<<dim3(288), dim3(256), 0, stream>>>(cond, cmask, Wc, W1, Wlin,
                                                    dv, dv_out, W1t, Wlt);
    k_mlp     <<<dim3(DEGN * 64), dim3(256), 0, stream>>>(x, xmask, b1, blin, dv,
                                                          W1t, Wlt, yv);
    k_contract<<<dim3(BB * NN / 4), dim3(256), 0, stream>>>(yv, out);
}

// Round 12
// 71.101 us; speedup vs baseline: 1.5959x; 1.5959x over previous
//
#include <hip/hip_runtime.h>
#include <hip/hip_bf16.h>
#include <math.h>
#include <string.h>

#define BB   16
#define NN   128
#define NCC  32
#define HH   256
#define AA   64
#define DEGN 3
#define BNR  (BB*NN)   // 2048 rows

typedef __bf16 bf16x8 __attribute__((ext_vector_type(8)));
typedef float  f32x16 __attribute__((ext_vector_type(16)));

__device__ __forceinline__ unsigned int pk2(float lo, float hi) {
    __hip_bfloat162 h2 = __float22bfloat162_rn(make_float2(lo, hi));
    unsigned int u;
    memcpy(&u, &h2, 4);
    return u;
}
__device__ __forceinline__ unsigned short bfbits(float f) {
    __hip_bfloat16 h = __float2bfloat16(f);
    unsigned short u;
    memcpy(&u, &h, 2);
    return u;
}

// ---------------------------------------------------------------------------
// Kernel 1 (k_head): fused prep (unchanged from round 9).
// ---------------------------------------------------------------------------
__global__ __launch_bounds__(256) void k_head(const float* __restrict__ cond,
                                              const float* __restrict__ cmask,
                                              const float* __restrict__ Wc,
                                              const float* __restrict__ W1,
                                              const float* __restrict__ Wlin,
                                              float* __restrict__ dv,
                                              float* __restrict__ dv_out,
                                              unsigned short* __restrict__ W1t,
                                              unsigned short* __restrict__ Wlt) {
    __shared__ float shm[32 * 33];
    const int bid = blockIdx.x, t = threadIdx.x;

    if (bid < 48) {
        const int d = bid >> 4, b = bid & 15;
        float s = 0.f, ms = 0.f;
        for (int c = 0; c < NCC; ++c) {
            float mk = cmask[b * NCC + c];
            s  += cond[(b * NCC + c) * HH + t] * mk;
            ms += mk;
        }
        shm[t] = s / fmaxf(ms, 1.0f);
        __syncthreads();
        const float* Wd = Wc + (size_t)d * HH * HH;
        float acc = 0.f;
        for (int k = 0; k < HH; ++k) acc += shm[k] * Wd[k * HH + t];
        int idx = (d * BB + b) * HH + t;
        dv[idx]     = acc;
        dv_out[idx] = acc;
    } else if (bid < 240) {
        const int q = bid - 48;
        const int d = q >> 6, r2 = q & 63, tk = r2 >> 3, tn = r2 & 7;
        float (*tile)[33] = (float (*)[33])shm;
        #pragma unroll
        for (int p = 0; p < 4; ++p) {
            int kr = p * 8 + (t >> 5), nr = t & 31;
            tile[kr][nr] = W1[((size_t)d * HH + tk * 32 + kr) * HH + tn * 32 + nr];
        }
        __syncthreads();
        #pragma unroll
        for (int p = 0; p < 4; ++p) {
            int nr = p * 8 + (t >> 5), kr = t & 31;
            W1t[((size_t)d * HH + tn * 32 + nr) * HH + tk * 32 + kr] =
                bfbits(tile[kr][nr]);
        }
    } else {
        const int q = bid - 240;
        const int d = q >> 4, r3 = q & 15, tk = r3 >> 1, ta = r3 & 1;
        float (*tile)[33] = (float (*)[33])shm;
        #pragma unroll
        for (int p = 0; p < 4; ++p) {
            int kr = p * 8 + (t >> 5), ar = t & 31;
            tile[kr][ar] = Wlin[((size_t)d * HH + tk * 32 + kr) * AA + ta * 32 + ar];
        }
        __syncthreads();
        #pragma unroll
        for (int p = 0; p < 4; ++p) {
            int ar = p * 8 + (t >> 5), kr = t & 31;
            Wlt[((size_t)d * AA + ta * 32 + ar) * HH + tk * 32 + kr] =
                bfbits(tile[kr][ar]);
        }
    }
}

// ---------------------------------------------------------------------------
// Kernel 2 (k_mlp): fused encoder+linear via bf16 MFMA (unchanged from r9).
// ---------------------------------------------------------------------------
__global__ __launch_bounds__(256) void k_mlp(const float* __restrict__ x,
                                             const float* __restrict__ xmask,
                                             const float* __restrict__ b1,
                                             const float* __restrict__ blin,
                                             const float* __restrict__ dv,
                                             const unsigned short* __restrict__ W1t,
                                             const unsigned short* __restrict__ Wlt,
                                             float* __restrict__ yv) {
    __shared__ __align__(16) char ldsA[32 * 512];
    __shared__ float ps[2][32][68];

    const int t = threadIdx.x;
    const int d = blockIdx.x >> 6, rt = blockIdx.x & 63;
    const int row0 = rt * 32;
    const int b = row0 >> 7;
    const int lane = t & 63, wid = t >> 6;
    const int rl5 = lane & 31, h2v = lane >> 5;

    #pragma unroll
    for (int it = 0; it < 8; ++it) {
        const int r = wid * 8 + it;
        const float4 v = *(const float4*)&x[(size_t)(row0 + r) * HH + lane * 4];
        uint2 u = make_uint2(pk2(v.x, v.y), pk2(v.z, v.w));
        *(uint2*)(ldsA + r * 512 + ((lane * 8) ^ ((r & 7) << 4))) = u;
    }
    __syncthreads();

    f32x16 acc1[2];
    #pragma unroll
    for (int nt = 0; nt < 2; ++nt)
        #pragma unroll
        for (int e = 0; e < 16; ++e) acc1[nt][e] = 0.f;

    #pragma unroll
    for (int ks = 0; ks < 16; ++ks) {
        bf16x8 af = *(const bf16x8*)(ldsA + rl5 * 512 +
                      ((ks * 32 + h2v * 16) ^ ((rl5 & 7) << 4)));
        #pragma unroll
        for (int nt = 0; nt < 2; ++nt) {
            const int n = wid * 64 + nt * 32 + rl5;
            bf16x8 bf = *(const bf16x8*)(W1t +
                          ((size_t)d * HH + n) * HH + ks * 16 + h2v * 8);
            acc1[nt] = __builtin_amdgcn_mfma_f32_32x32x16_bf16(af, bf, acc1[nt], 0, 0, 0);
        }
    }
    __syncthreads();

    #pragma unroll
    for (int nt = 0; nt < 2; ++nt) {
        const int col = wid * 64 + nt * 32 + rl5;
        const float add = b1[d * HH + col] + dv[(d * BB + b) * HH + col];
        #pragma unroll
        for (int e = 0; e < 16; ++e) {
            const int row = (e & 3) + 8 * (e >> 2) + 4 * h2v;
            float v = acc1[nt][e] + add;
            float u = 0.7978845608028654f * (v + 0.044715f * v * v * v);
            float g = 0.5f * v * (1.0f + tanhf(u));
            *(unsigned short*)(ldsA + row * 512 + ((col * 2) ^ ((row & 7) << 4))) =
                bfbits(g);
        }
    }
    __syncthreads();

    const int qc = wid >> 1, kh = wid & 1;
    f32x16 acc2;
    #pragma unroll
    for (int e = 0; e < 16; ++e) acc2[e] = 0.f;
    #pragma unroll
    for (int ks = 0; ks < 8; ++ks) {
        const int kk = kh * 8 + ks;
        bf16x8 af = *(const bf16x8*)(ldsA + rl5 * 512 +
                      ((kk * 32 + h2v * 16) ^ ((rl5 & 7) << 4)));
        bf16x8 bf = *(const bf16x8*)(Wlt +
                      ((size_t)d * AA + qc * 32 + rl5) * HH + kk * 16 + h2v * 8);
        acc2 = __builtin_amdgcn_mfma_f32_32x32x16_bf16(af, bf, acc2, 0, 0, 0);
    }
    #pragma unroll
    for (int e = 0; e < 16; ++e) {
        const int row = (e & 3) + 8 * (e >> 2) + 4 * h2v;
        ps[kh][row][qc * 32 + rl5] = acc2[e];
    }
    __syncthreads();

    #pragma unroll
    for (int j = 0; j < 8; ++j) {
        const int idx = t * 8 + j;
        const int row = idx >> 6, a = idx & 63;
        float v = ps[0][row][a] + ps[1][row][a] + blin[d * AA + a];
        v *= xmask[row0 + row];
        yv[((size_t)d * BNR + row0 + row) * AA + a] = v;
    }
}

// ---------------------------------------------------------------------------
// Kernel 3 (k_contract): split-A phasing, 48KB LDS -> 3 blocks/CU, VGPR<=128.
// Same algebra & accumulation order as r8-r10 (bit-identical):
// out*4096 = A1 B1^T + B1 A1^T + A2 B2^T + B2 A2^T per (b,x).
// LDS = A(16K) | B1(16K) | B2(16K). B1/B2 staged once per block (2 x each).
// Per x: stage A1 -> bar -> p0,p1 -> bar -> stage A2 (in place) -> bar ->
// p2,p3 -> bar -> wave-local epilogue in 4 quarter-phases through the
// wave's own 4KB A-slice (full-row 1KB-contiguous float4 stores).
// vmcnt never waited mid-kernel. NOTE r11 lesson: no big reg arrays —
// VGPR must stay <=128 (129+ halves occupancy; spills cost 2x).
// ---------------------------------------------------------------------------
__device__ __forceinline__ void lds_fence_barrier() {
    asm volatile("s_waitcnt lgkmcnt(0)" ::: "memory");
    __builtin_amdgcn_s_barrier();
    __builtin_amdgcn_sched_barrier(0);
}
__device__ __forceinline__ void lds_wave_wait() {
    asm volatile("s_waitcnt lgkmcnt(0)" ::: "memory");
    __builtin_amdgcn_sched_barrier(0);
}

#define LROW 128   // bytes per LDS row (64 bf16)

__global__ __launch_bounds__(256, 4) void k_contract(const float* __restrict__ yv,
                                                     float* __restrict__ outp) {
    __shared__ __align__(16) char lds[3 * 128 * LROW];   // A | B1 | B2
    char* Ab  = lds;
    char* B1b = lds + 1 * 128 * LROW;
    char* B2b = lds + 2 * 128 * LROW;

    const int t  = threadIdx.x;
    const int b  = blockIdx.x >> 6;       // 64 x-groups (2 x each) per batch
    const int xg = blockIdx.x & 63;

    const float* y0p = yv + (size_t)(0 * BNR + b * NN) * AA;
    const float* y1p = yv + (size_t)(1 * BNR + b * NN) * AA;
    const float* y2p = yv + (size_t)(2 * BNR + b * NN) * AA;

    const int lane = t & 63;
    const int wid  = t >> 6;
    const int li   = lane & 31;
    const int rh   = lane >> 5;
    const int rl5  = lane & 31, h2v = lane >> 5;
    const int wy   = wid * 32;            // this wave's output row stripe

    // ---- stage B1 = Y2, B2 = Y1 once per block ----
    #pragma unroll
    for (int it = 0; it < 16; ++it) {
        const int r   = wid * 32 + it * 2 + rh;
        const int swz = (r & 7) << 4;
        const float2 v1 = *(const float2*)&y1p[r * AA + 2 * li];
        const float2 v2 = *(const float2*)&y2p[r * AA + 2 * li];
        *(unsigned int*)(B1b + r * LROW + ((4 * li) ^ swz)) = pk2(v2.x, v2.y);
        *(unsigned int*)(B2b + r * LROW + ((4 * li) ^ swz)) = pk2(v1.x, v1.y);
    }
    // (covered by xi=0's first barrier)

    const float inv = 1.0f / 4096.0f;
    char* scr = Ab + wid * 4096;          // wave-private epilogue scratch (4KB)

    for (int xi = 0; xi < 2; ++xi) {
        const int xr = xg * 2 + xi;
        const float s0 = y0p[xr * AA + lane];
        const float s1v = y1p[xr * AA + lane];
        const float s2v = y2p[xr * AA + lane];
        const float s0a = __shfl(s0, 2 * li),  s0b = __shfl(s0, 2 * li + 1);
        const float s1a = __shfl(s1v, 2 * li), s1b = __shfl(s1v, 2 * li + 1);
        const float s2a = __shfl(s2v, 2 * li), s2b = __shfl(s2v, 2 * li + 1);

        f32x16 acc[4];
        #pragma unroll
        for (int ni = 0; ni < 4; ++ni)
            #pragma unroll
            for (int e = 0; e < 16; ++e) acc[ni][e] = 0.f;

        // ---- stage A1 into Ab (own rows) ----
        #pragma unroll
        for (int it = 0; it < 16; ++it) {
            const int r   = wid * 32 + it * 2 + rh;
            const int swz = (r & 7) << 4;
            const float2 v0 = *(const float2*)&y0p[r * AA + 2 * li];
            const float2 v1 = *(const float2*)&y1p[r * AA + 2 * li];
            *(unsigned int*)(Ab + r * LROW + ((4 * li) ^ swz)) =
                pk2(s0a * v1.x + s1a * v0.x, s0b * v1.y + s1b * v0.y);
        }
        lds_fence_barrier();   // bar1: A1 staged (xi=0: also B1/B2)

        // p0: A1 (own rows) x B1^T (all rows)
        #pragma unroll
        for (int ks = 0; ks < 4; ++ks) {
            const int arow = wy + rl5;
            bf16x8 af = *(const bf16x8*)(Ab + arow * LROW +
                          ((ks * 32 + h2v * 16) ^ ((arow & 7) << 4)));
            #pragma unroll
            for (int ni = 0; ni < 4; ++ni) {
                const int brow = ni * 32 + rl5;
                bf16x8 bf = *(const bf16x8*)(B1b + brow * LROW +
                              ((ks * 32 + h2v * 16) ^ ((brow & 7) << 4)));
                acc[ni] = __builtin_amdgcn_mfma_f32_32x32x16_bf16(
                    af, bf, acc[ni], 0, 0, 0);
            }
        }
        // p1: B1 (own row) x A1^T (all rows)
        #pragma unroll
        for (int ks = 0; ks < 4; ++ks) {
            const int arow = wy + rl5;
            bf16x8 af = *(const bf16x8*)(B1b + arow * LROW +
                          ((ks * 32 + h2v * 16) ^ ((arow & 7) << 4)));
            #pragma unroll
            for (int ni = 0; ni < 4; ++ni) {
                const int brow = ni * 32 + rl5;
                bf16x8 bf = *(const bf16x8*)(Ab + brow * LROW +
                              ((ks * 32 + h2v * 16) ^ ((brow & 7) << 4)));
                acc[ni] = __builtin_amdgcn_mfma_f32_32x32x16_bf16(
                    af, bf, acc[ni], 0, 0, 0);
            }
        }
        lds_fence_barrier();   // bar2: A1 reads done -> restage

        // ---- stage A2 into Ab (own rows) ----
        #pragma unroll
        for (int it = 0; it < 16; ++it) {
            const int r   = wid * 32 + it * 2 + rh;
            const int swz = (r & 7) << 4;
            const float2 v0 = *(const float2*)&y0p[r * AA + 2 * li];
            *(unsigned int*)(Ab + r * LROW + ((4 * li) ^ swz)) =
                pk2(s2a * v0.x, s2b * v0.y);
        }
        lds_fence_barrier();   // bar3: A2 staged

        // p2: A2 (own rows) x B2^T
        #pragma unroll
        for (int ks = 0; ks < 4; ++ks) {
            const int arow = wy + rl5;
            bf16x8 af = *(const bf16x8*)(Ab + arow * LROW +
                          ((ks * 32 + h2v * 16) ^ ((arow & 7) << 4)));
            #pragma unroll
            for (int ni = 0; ni < 4; ++ni) {
                const int brow = ni * 32 + rl5;
                bf16x8 bf = *(const bf16x8*)(B2b + brow * LROW +
                              ((ks * 32 + h2v * 16) ^ ((brow & 7) << 4)));
                acc[ni] = __builtin_amdgcn_mfma_f32_32x32x16_bf16(
                    af, bf, acc[ni], 0, 0, 0);
            }
        }
        // p3: B2 (own row) x A2^T
        #pragma unroll
        for (int ks = 0; ks < 4; ++ks) {
            const int arow = wy + rl5;
            bf16x8 af = *(const bf16x8*)(B2b + arow * LROW +
                          ((ks * 32 + h2v * 16) ^ ((arow & 7) << 4)));
            #pragma unroll
            for (int ni = 0; ni < 4; ++ni) {
                const int brow = ni * 32 + rl5;
                bf16x8 bf = *(const bf16x8*)(Ab + brow * LROW +
                              ((ks * 32 + h2v * 16) ^ ((brow & 7) << 4)));
                acc[ni] = __builtin_amdgcn_mfma_f32_32x32x16_bf16(
                    af, bf, acc[ni], 0, 0, 0);
            }
        }
        lds_fence_barrier();   // bar4: all A reads done -> scratch usable

        // ---- wave-local epilogue: 4 quarter-phases of 8 rows each ----
        // acc[ni][e] -> out row wy + 8*(e>>2) + (e&3) + 4*h2v, col ni*32+rl5
        float* osl = outp + ((size_t)(b * NN + xr)) * (NN * NN);
        #pragma unroll
        for (int q = 0; q < 4; ++q) {
            #pragma unroll
            for (int ni = 0; ni < 4; ++ni) {
                #pragma unroll
                for (int j = 0; j < 4; ++j) {
                    const int e    = q * 4 + j;
                    const int srow = j + 4 * h2v;            // 0..7
                    *(float*)(scr + srow * 512 + (ni * 32 + rl5) * 4) =
                        acc[ni][e] * inv;
                }
            }
            lds_wave_wait();
            #pragma unroll
            for (int it2 = 0; it2 < 4; ++it2) {
                const int srow = it2 * 2 + rh;               // 0..7
                float4 v = *(const float4*)(scr + srow * 512 + rl5 * 16);
                *(float4*)&osl[(size_t)(wy + q * 8 + srow) * NN + rl5 * 4] = v;
            }
            lds_wave_wait();
        }
        // next xi: own A1 staging overwrites own scratch rows (program order)
    }
}

// ---------------------------------------------------------------------------
extern "C" void kernel_launch(void* const* d_in, const int* in_sizes, int n_in,
                              void* d_out, int out_size, void* d_ws, size_t ws_size,
                              hipStream_t stream) {
    const float* x     = (const float*)d_in[0];
    const float* xmask = (const float*)d_in[1];
    const float* cond  = (const float*)d_in[2];
    const float* cmask = (const float*)d_in[3];
    const float* W1    = (const float*)d_in[4];
    const float* b1    = (const float*)d_in[5];
    const float* Wc    = (const float*)d_in[6];
    const float* Wlin  = (const float*)d_in[7];
    const float* blin  = (const float*)d_in[8];

    float* out = (float*)d_out;
    float* ws  = (float*)d_ws;

    float* dv  = ws;                               // 3*16*256 f
    float* yv  = ws + 12288;                       // 3*2048*64 f
    unsigned short* W1t = (unsigned short*)((char*)d_ws + (size_t)(12288 + 393216) * 4);
    unsigned short* Wlt = W1t + (size_t)DEGN * HH * HH;
    float* dv_out = out + (size_t)BB * NN * NN * NN;

    k_head    <<<dim3(288), dim3(256), 0, stream>>>(cond, cmask, Wc, W1, Wlin,
                                                    dv, dv_out, W1t, Wlt);
    k_mlp     <<<dim3(DEGN * 64), dim3(256), 0, stream>>>(x, xmask, b1, blin, dv,
                                                          W1t, Wlt, yv);
    k_contract<<<dim3(BB * NN / 2), dim3(256), 0, stream>>>(yv, out);
}

// Round 13
// 57.153 us; speedup vs baseline: 1.9854x; 1.2441x over previous
//
#include <hip/hip_runtime.h>
#include <hip/hip_bf16.h>
#include <math.h>
#include <string.h>

#define BB   16
#define NN   128
#define NCC  32
#define HH   256
#define AA   64
#define DEGN 3
#define BNR  (BB*NN)   // 2048 rows

typedef __bf16 bf16x8 __attribute__((ext_vector_type(8)));
typedef float  f32x16 __attribute__((ext_vector_type(16)));

__device__ __forceinline__ unsigned int pk2(float lo, float hi) {
    __hip_bfloat162 h2 = __float22bfloat162_rn(make_float2(lo, hi));
    unsigned int u;
    memcpy(&u, &h2, 4);
    return u;
}
__device__ __forceinline__ float2 unpk(unsigned int u) {
    return make_float2(__uint_as_float(u << 16),
                       __uint_as_float(u & 0xffff0000u));
}
__device__ __forceinline__ unsigned short bfbits(float f) {
    __hip_bfloat16 h = __float2bfloat16(f);
    unsigned short u;
    memcpy(&u, &h, 2);
    return u;
}

// ---------------------------------------------------------------------------
// Kernel 1 (k_head): fused prep (unchanged from round 9).
// ---------------------------------------------------------------------------
__global__ __launch_bounds__(256) void k_head(const float* __restrict__ cond,
                                              const float* __restrict__ cmask,
                                              const float* __restrict__ Wc,
                                              const float* __restrict__ W1,
                                              const float* __restrict__ Wlin,
                                              float* __restrict__ dv,
                                              float* __restrict__ dv_out,
                                              unsigned short* __restrict__ W1t,
                                              unsigned short* __restrict__ Wlt) {
    __shared__ float shm[32 * 33];
    const int bid = blockIdx.x, t = threadIdx.x;

    if (bid < 48) {
        const int d = bid >> 4, b = bid & 15;
        float s = 0.f, ms = 0.f;
        for (int c = 0; c < NCC; ++c) {
            float mk = cmask[b * NCC + c];
            s  += cond[(b * NCC + c) * HH + t] * mk;
            ms += mk;
        }
        shm[t] = s / fmaxf(ms, 1.0f);
        __syncthreads();
        const float* Wd = Wc + (size_t)d * HH * HH;
        float acc = 0.f;
        for (int k = 0; k < HH; ++k) acc += shm[k] * Wd[k * HH + t];
        int idx = (d * BB + b) * HH + t;
        dv[idx]     = acc;
        dv_out[idx] = acc;
    } else if (bid < 240) {
        const int q = bid - 48;
        const int d = q >> 6, r2 = q & 63, tk = r2 >> 3, tn = r2 & 7;
        float (*tile)[33] = (float (*)[33])shm;
        #pragma unroll
        for (int p = 0; p < 4; ++p) {
            int kr = p * 8 + (t >> 5), nr = t & 31;
            tile[kr][nr] = W1[((size_t)d * HH + tk * 32 + kr) * HH + tn * 32 + nr];
        }
        __syncthreads();
        #pragma unroll
        for (int p = 0; p < 4; ++p) {
            int nr = p * 8 + (t >> 5), kr = t & 31;
            W1t[((size_t)d * HH + tn * 32 + nr) * HH + tk * 32 + kr] =
                bfbits(tile[kr][nr]);
        }
    } else {
        const int q = bid - 240;
        const int d = q >> 4, r3 = q & 15, tk = r3 >> 1, ta = r3 & 1;
        float (*tile)[33] = (float (*)[33])shm;
        #pragma unroll
        for (int p = 0; p < 4; ++p) {
            int kr = p * 8 + (t >> 5), ar = t & 31;
            tile[kr][ar] = Wlin[((size_t)d * HH + tk * 32 + kr) * AA + ta * 32 + ar];
        }
        __syncthreads();
        #pragma unroll
        for (int p = 0; p < 4; ++p) {
            int ar = p * 8 + (t >> 5), kr = t & 31;
            Wlt[((size_t)d * AA + ta * 32 + ar) * HH + tk * 32 + kr] =
                bfbits(tile[kr][ar]);
        }
    }
}

// ---------------------------------------------------------------------------
// Kernel 2 (k_mlp): fused encoder+linear via bf16 MFMA (unchanged from r9).
// ---------------------------------------------------------------------------
__global__ __launch_bounds__(256) void k_mlp(const float* __restrict__ x,
                                             const float* __restrict__ xmask,
                                             const float* __restrict__ b1,
                                             const float* __restrict__ blin,
                                             const float* __restrict__ dv,
                                             const unsigned short* __restrict__ W1t,
                                             const unsigned short* __restrict__ Wlt,
                                             float* __restrict__ yv) {
    __shared__ __align__(16) char ldsA[32 * 512];
    __shared__ float ps[2][32][68];

    const int t = threadIdx.x;
    const int d = blockIdx.x >> 6, rt = blockIdx.x & 63;
    const int row0 = rt * 32;
    const int b = row0 >> 7;
    const int lane = t & 63, wid = t >> 6;
    const int rl5 = lane & 31, h2v = lane >> 5;

    #pragma unroll
    for (int it = 0; it < 8; ++it) {
        const int r = wid * 8 + it;
        const float4 v = *(const float4*)&x[(size_t)(row0 + r) * HH + lane * 4];
        uint2 u = make_uint2(pk2(v.x, v.y), pk2(v.z, v.w));
        *(uint2*)(ldsA + r * 512 + ((lane * 8) ^ ((r & 7) << 4))) = u;
    }
    __syncthreads();

    f32x16 acc1[2];
    #pragma unroll
    for (int nt = 0; nt < 2; ++nt)
        #pragma unroll
        for (int e = 0; e < 16; ++e) acc1[nt][e] = 0.f;

    #pragma unroll
    for (int ks = 0; ks < 16; ++ks) {
        bf16x8 af = *(const bf16x8*)(ldsA + rl5 * 512 +
                      ((ks * 32 + h2v * 16) ^ ((rl5 & 7) << 4)));
        #pragma unroll
        for (int nt = 0; nt < 2; ++nt) {
            const int n = wid * 64 + nt * 32 + rl5;
            bf16x8 bf = *(const bf16x8*)(W1t +
                          ((size_t)d * HH + n) * HH + ks * 16 + h2v * 8);
            acc1[nt] = __builtin_amdgcn_mfma_f32_32x32x16_bf16(af, bf, acc1[nt], 0, 0, 0);
        }
    }
    __syncthreads();

    #pragma unroll
    for (int nt = 0; nt < 2; ++nt) {
        const int col = wid * 64 + nt * 32 + rl5;
        const float add = b1[d * HH + col] + dv[(d * BB + b) * HH + col];
        #pragma unroll
        for (int e = 0; e < 16; ++e) {
            const int row = (e & 3) + 8 * (e >> 2) + 4 * h2v;
            float v = acc1[nt][e] + add;
            float u = 0.7978845608028654f * (v + 0.044715f * v * v * v);
            float g = 0.5f * v * (1.0f + tanhf(u));
            *(unsigned short*)(ldsA + row * 512 + ((col * 2) ^ ((row & 7) << 4))) =
                bfbits(g);
        }
    }
    __syncthreads();

    const int qc = wid >> 1, kh = wid & 1;
    f32x16 acc2;
    #pragma unroll
    for (int e = 0; e < 16; ++e) acc2[e] = 0.f;
    #pragma unroll
    for (int ks = 0; ks < 8; ++ks) {
        const int kk = kh * 8 + ks;
        bf16x8 af = *(const bf16x8*)(ldsA + rl5 * 512 +
                      ((kk * 32 + h2v * 16) ^ ((rl5 & 7) << 4)));
        bf16x8 bf = *(const bf16x8*)(Wlt +
                      ((size_t)d * AA + qc * 32 + rl5) * HH + kk * 16 + h2v * 8);
        acc2 = __builtin_amdgcn_mfma_f32_32x32x16_bf16(af, bf, acc2, 0, 0, 0);
    }
    #pragma unroll
    for (int e = 0; e < 16; ++e) {
        const int row = (e & 3) + 8 * (e >> 2) + 4 * h2v;
        ps[kh][row][qc * 32 + rl5] = acc2[e];
    }
    __syncthreads();

    #pragma unroll
    for (int j = 0; j < 8; ++j) {
        const int idx = t * 8 + j;
        const int row = idx >> 6, a = idx & 63;
        float v = ps[0][row][a] + ps[1][row][a] + blin[d * AA + a];
        v *= xmask[row0 + row];
        yv[((size_t)d * BNR + row0 + row) * AA + a] = v;
    }
}

// ---------------------------------------------------------------------------
// Kernel 3 (k_contract): ZERO global loads in the xi loop.
// vmcnt retires IN ORDER: any load issued after stores waits for the stores
// to drain. r4-r12's xi loops all loaded yv after storing out -> store drain
// serialized with compute (the ~50us plateau). Fix: prologue stages Y0/Y2/Y1
// to LDS as bf16 (before any store) and prefetches all 12 s-scalars to regs;
// per xi A1/A2 are CONSTRUCTED from LDS (ds_read -> unpack -> fma -> pk2 ->
// ds_write). The only vmcnt ops in the loop are the 16 output stores, which
// are never waited on -> stores drain under next xi's construct+MFMA.
// Algebra/order unchanged: out*4096 = A1 B1^T + B1 A1^T + A2 B2^T + B2 A2^T.
// LDS 80KB: A1|A2|Y0|B1(=Y2)|B2(=Y1). Grid 512 (4 x/block), 2 blocks/CU.
// VGPR kept <=128 (r11 lesson).
// ---------------------------------------------------------------------------
__device__ __forceinline__ void lds_fence_barrier() {
    asm volatile("s_waitcnt lgkmcnt(0)" ::: "memory");
    __builtin_amdgcn_s_barrier();
    __builtin_amdgcn_sched_barrier(0);
}
__device__ __forceinline__ void lds_wave_wait() {
    asm volatile("s_waitcnt lgkmcnt(0)" ::: "memory");
    __builtin_amdgcn_sched_barrier(0);
}

#define LROW 128   // bytes per LDS row (64 bf16)

__global__ __launch_bounds__(256, 2) void k_contract(const float* __restrict__ yv,
                                                     float* __restrict__ outp) {
    __shared__ __align__(16) char lds[5 * 128 * LROW];   // 80KB
    char* A1b = lds;
    char* A2b = lds + 1 * 128 * LROW;
    char* Y0b = lds + 2 * 128 * LROW;
    char* B1b = lds + 3 * 128 * LROW;    // = Y2
    char* B2b = lds + 4 * 128 * LROW;    // = Y1

    const int t  = threadIdx.x;
    const int b  = blockIdx.x >> 5;
    const int xg = blockIdx.x & 31;

    const float* y0p = yv + (size_t)(0 * BNR + b * NN) * AA;
    const float* y1p = yv + (size_t)(1 * BNR + b * NN) * AA;
    const float* y2p = yv + (size_t)(2 * BNR + b * NN) * AA;

    const int lane = t & 63;
    const int wid  = t >> 6;
    const int li   = lane & 31;
    const int rh   = lane >> 5;
    const int rl5  = lane & 31, h2v = lane >> 5;
    const int wy   = wid * 32;            // this wave's output row stripe

    // ---- prologue: prefetch s for all 4 xi (12 regs; loads BEFORE stores) ----
    float s0v[4], s1v[4], s2v[4];
    #pragma unroll
    for (int xi = 0; xi < 4; ++xi) {
        const int xr = xg * 4 + xi;
        s0v[xi] = y0p[xr * AA + lane];
        s1v[xi] = y1p[xr * AA + lane];
        s2v[xi] = y2p[xr * AA + lane];
    }

    // ---- prologue: stage Y0, B1=Y2, B2=Y1 as bf16 (once per block) ----
    #pragma unroll
    for (int it = 0; it < 16; ++it) {
        const int r   = wid * 32 + it * 2 + rh;
        const int swz = (r & 7) << 4;
        const int off = r * LROW + ((4 * li) ^ swz);
        const float2 v0 = *(const float2*)&y0p[r * AA + 2 * li];
        const float2 v1 = *(const float2*)&y1p[r * AA + 2 * li];
        const float2 v2 = *(const float2*)&y2p[r * AA + 2 * li];
        *(unsigned int*)(Y0b + off) = pk2(v0.x, v0.y);
        *(unsigned int*)(B1b + off) = pk2(v2.x, v2.y);
        *(unsigned int*)(B2b + off) = pk2(v1.x, v1.y);
    }

    const float inv = 1.0f / 4096.0f;
    // wave-private epilogue scratch = own A1/A2 row slices (4KB each)
    char* scr1 = A1b + wid * 4096;
    char* scr2 = A2b + wid * 4096;

    #pragma unroll
    for (int xi = 0; xi < 4; ++xi) {
        const int xr = xg * 4 + xi;
        const float s0a = __shfl(s0v[xi], 2 * li), s0b = __shfl(s0v[xi], 2 * li + 1);
        const float s1a = __shfl(s1v[xi], 2 * li), s1b = __shfl(s1v[xi], 2 * li + 1);
        const float s2a = __shfl(s2v[xi], 2 * li), s2b = __shfl(s2v[xi], 2 * li + 1);

        if (xi == 0) lds_fence_barrier();   // Y panels visible to all waves

        // ---- construct A1/A2 (own rows) from LDS — LGKM ops only ----
        #pragma unroll
        for (int it = 0; it < 16; ++it) {
            const int r   = wid * 32 + it * 2 + rh;
            const int swz = (r & 7) << 4;
            const int off = r * LROW + ((4 * li) ^ swz);
            const float2 y0 = unpk(*(const unsigned int*)(Y0b + off));
            const float2 y1 = unpk(*(const unsigned int*)(B2b + off));
            *(unsigned int*)(A1b + off) =
                pk2(s0a * y1.x + s1a * y0.x, s0b * y1.y + s1b * y0.y);
            *(unsigned int*)(A2b + off) = pk2(s2a * y0.x, s2b * y0.y);
        }
        lds_fence_barrier();   // bar1: A staged

        // ---- MFMA, order identical to r10: p0,p1,p2,p3 x ks x ni ----
        f32x16 acc[4];
        #pragma unroll
        for (int ni = 0; ni < 4; ++ni)
            #pragma unroll
            for (int e = 0; e < 16; ++e) acc[ni][e] = 0.f;

        #pragma unroll
        for (int p = 0; p < 4; ++p) {
            const char* Ua = (p == 0) ? A1b : (p == 1) ? B1b : (p == 2) ? A2b : B2b;
            const char* Va = (p == 0) ? B1b : (p == 1) ? A1b : (p == 2) ? B2b : A2b;
            #pragma unroll
            for (int ks = 0; ks < 4; ++ks) {
                const int arow = wy + rl5;
                bf16x8 af = *(const bf16x8*)(Ua + arow * LROW +
                              ((ks * 32 + h2v * 16) ^ ((arow & 7) << 4)));
                #pragma unroll
                for (int ni = 0; ni < 4; ++ni) {
                    const int brow = ni * 32 + rl5;
                    bf16x8 bf = *(const bf16x8*)(Va + brow * LROW +
                                  ((ks * 32 + h2v * 16) ^ ((brow & 7) << 4)));
                    acc[ni] = __builtin_amdgcn_mfma_f32_32x32x16_bf16(
                        af, bf, acc[ni], 0, 0, 0);
                }
            }
        }
        lds_fence_barrier();   // bar2: all A reads done -> scratch usable

        // ---- wave-local epilogue (r10 scheme): only vmcnt ops = stores ----
        float* osl = outp + ((size_t)(b * NN + xr)) * (NN * NN);
        #pragma unroll
        for (int half = 0; half < 2; ++half) {
            #pragma unroll
            for (int ni = 0; ni < 4; ++ni) {
                const int colb = ni * 32 + rl5;
                #pragma unroll
                for (int e2 = 0; e2 < 8; ++e2) {
                    const int e    = half * 8 + e2;
                    const int rloc = (e2 & 3) + 8 * (e2 >> 2) + 4 * h2v;
                    char* reg = (e2 < 4) ? scr1 : scr2;
                    *(float*)(reg + ((rloc & 7) * 512) + colb * 4) =
                        acc[ni][e] * inv;
                }
            }
            lds_wave_wait();
            #pragma unroll
            for (int it2 = 0; it2 < 8; ++it2) {
                const int rloc = it2 * 2 + rh;
                const char* reg = (it2 < 4) ? scr1 : scr2;
                float4 v = *(const float4*)(reg + ((rloc & 7) * 512) + rl5 * 16);
                *(float4*)&osl[(size_t)(wy + half * 16 + rloc) * NN + rl5 * 4] = v;
            }
            lds_wave_wait();
        }
        // next xi: construct overwrites own scratch rows (wave program order)
    }
}

// ---------------------------------------------------------------------------
extern "C" void kernel_launch(void* const* d_in, const int* in_sizes, int n_in,
                              void* d_out, int out_size, void* d_ws, size_t ws_size,
                              hipStream_t stream) {
    const float* x     = (const float*)d_in[0];
    const float* xmask = (const float*)d_in[1];
    const float* cond  = (const float*)d_in[2];
    const float* cmask = (const float*)d_in[3];
    const float* W1    = (const float*)d_in[4];
    const float* b1    = (const float*)d_in[5];
    const float* Wc    = (const float*)d_in[6];
    const float* Wlin  = (const float*)d_in[7];
    const float* blin  = (const float*)d_in[8];

    float* out = (float*)d_out;
    float* ws  = (float*)d_ws;

    float* dv  = ws;                               // 3*16*256 f
    float* yv  = ws + 12288;                       // 3*2048*64 f
    unsigned short* W1t = (unsigned short*)((char*)d_ws + (size_t)(12288 + 393216) * 4);
    unsigned short* Wlt = W1t + (size_t)DEGN * HH * HH;
    float* dv_out = out + (size_t)BB * NN * NN * NN;

    k_head    <<<dim3(288), dim3(256), 0, stream>>>(cond, cmask, Wc, W1, Wlin,
                                                    dv, dv_out, W1t, Wlt);
    k_mlp     <<<dim3(DEGN * 64), dim3(256), 0, stream>>>(x, xmask, b1, blin, dv,
                                                          W1t, Wlt, yv);
    k_contract<<<dim3(BB * NN / 4), dim3(256), 0, stream>>>(yv, out);
}